// Round 5
// baseline (522.292 us; speedup 1.0000x reference)
//
#include <hip/hip_runtime.h>
#include <math.h>

// Problem constants (fixed by reference setup_inputs)
#define NN  50000
#define EE  400000
#define DD  64
#define HH  4
#define HC  256      // H * C
#define EDD 16

__device__ __forceinline__ float gelu_exact(float x) {
    return 0.5f * x * (1.0f + erff(x * 0.70710678118654752440f));
}
// fast exp via v_exp_f32: exp(x)=2^(x*log2e). exp2(-inf)=0 preserved.
__device__ __forceinline__ float fast_exp(float x) {
    return __builtin_amdgcn_exp2f(x * 1.44269504088896340736f);
}

// DPP rotate-reduce within each 16-lane row: VALU-only (no ds_swizzle, no
// lgkmcnt). Sum of all 16 lanes of the row ends up in every lane.
template <int CTRL>
__device__ __forceinline__ float dpp_add(float x) {
    const int t = __builtin_amdgcn_update_dpp(0, __float_as_int(x), CTRL, 0xF, 0xF, true);
    return x + __int_as_float(t);
}
__device__ __forceinline__ float row_sum16(float x) {
    x = dpp_add<0x128>(x);   // row_ror:8
    x = dpp_add<0x124>(x);   // row_ror:4
    x = dpp_add<0x122>(x);   // row_ror:2
    x = dpp_add<0x121>(x);   // row_ror:1
    return x;
}

// ---------- fills ----------
__global__ void fill_u32(unsigned* __restrict__ p, unsigned v, int n) {
    int i = blockIdx.x * blockDim.x + threadIdx.x;
    int s = gridDim.x * blockDim.x;
    for (; i < n; i += s) p[i] = v;
}

// ---------- CSR build ----------
__global__ void hist_k(const int* __restrict__ ei, int* __restrict__ deg) {
    int e = blockIdx.x * 256 + threadIdx.x;
    if (e < EE) atomicAdd(&deg[ei[EE + e]], 1);
}
__global__ void scan1_k(const int* __restrict__ deg, int* __restrict__ rowptr,
                        int* __restrict__ bsum) {
    __shared__ int s[256];
    int t = threadIdx.x, i = blockIdx.x * 256 + t;
    int v = (i < NN) ? deg[i] : 0;
    s[t] = v; __syncthreads();
    for (int o = 1; o < 256; o <<= 1) {
        int u = (t >= o) ? s[t - o] : 0;
        __syncthreads();
        s[t] += u;
        __syncthreads();
    }
    if (i < NN) rowptr[i] = s[t] - v;
    if (t == 255) bsum[blockIdx.x] = s[255];
}
__global__ void scan2_k(int* __restrict__ bsum, int nb) {
    __shared__ int s[256];
    int t = threadIdx.x;
    int v = (t < nb) ? bsum[t] : 0;
    s[t] = v; __syncthreads();
    for (int o = 1; o < 256; o <<= 1) {
        int u = (t >= o) ? s[t - o] : 0;
        __syncthreads();
        s[t] += u;
        __syncthreads();
    }
    if (t < nb) bsum[t] = s[t] - v;
}
__global__ void scan3_k(int* __restrict__ rowptr, const int* __restrict__ bsum,
                        int* __restrict__ cursor) {
    int i = blockIdx.x * 256 + threadIdx.x;
    if (i < NN) {
        int r = rowptr[i] + bsum[blockIdx.x];
        rowptr[i] = r;
        cursor[i] = r;
    }
    if (i == 0) rowptr[NN] = EE;
}
// scatter srcs AND edge_attr into CSR order
__global__ void scatter_k(const int* __restrict__ ei, int* __restrict__ cursor,
                          const float* __restrict__ ea,
                          int* __restrict__ srcs, float* __restrict__ ea_s) {
    int e = blockIdx.x * 256 + threadIdx.x;
    if (e >= EE) return;
    int dst = ei[EE + e];
    int pos = atomicAdd(&cursor[dst], 1);
    srcs[pos] = ei[e];
    const float4* s4 = (const float4*)(ea + (long)e * EDD);
    float4* d4 = (float4*)(ea_s + (long)pos * EDD);
    d4[0] = s4[0]; d4[1] = s4[1]; d4[2] = s4[2]; d4[3] = s4[3];
}

// wave -> node-range precompute; also zeroes the srcs pad (valid node 0) so
// the fused kernel's masked x4 loop can gather without guards.
__global__ void wrange_k(const int* __restrict__ rowptr, int* __restrict__ wstart,
                         int* __restrict__ srcs, int nw, int cpe) {
    int w = blockIdx.x * 256 + threadIdx.x;
    if (blockIdx.x == 0 && threadIdx.x < 16) srcs[EE + threadIdx.x] = 0;
    if (w > nw) return;
    if (w == nw) { wstart[nw] = NN; return; }
    const int lo = w * cpe;
    int l = 0, r = NN;
    while (l < r) { int m = (l + r) >> 1; if (rowptr[m] >= lo) r = m; else l = m + 1; }
    wstart[w] = l;
}

// ---------- node GEMM (merged l+r): Y{l,r}[N,256] = X[N,64] @ W{l,r} + b{l,r} ----------
// X tile staged in LDS via per-lane coalesced loads (vmcnt path, not SMEM);
// ds_read broadcasts get fine-grained lgkmcnt waits. Both W sets in regs.
__global__ __launch_bounds__(256) void gemm_node_lr(
    const float* __restrict__ X,
    const float* __restrict__ Wl, const float* __restrict__ bl,
    const float* __restrict__ Wr, const float* __restrict__ br,
    float* __restrict__ Yl, float* __restrict__ Yr)
{
    __shared__ float xs[32][64];      // 8 KB tile
    const int tid  = threadIdx.x;
    const int col  = tid;
    const int base = blockIdx.x * 32;

    // stage X tile: 512 float4, 256 threads -> 2 each (coalesced, per-lane)
#pragma unroll
    for (int i = 0; i < 2; i++) {
        const int f   = tid + i * 256;         // float4 index 0..511
        const int r   = f >> 4;
        const int row = base + r;
        const int rr  = (row < NN) ? row : (NN - 1);
        const float4 v = *(const float4*)(X + (long)rr * 64 + ((f & 15) << 2));
        *(float4*)&xs[r][(f & 15) << 2] = v;
    }

    // both W columns into registers (128 VGPRs)
    float wl[64], wr[64];
#pragma unroll
    for (int k = 0; k < 64; k++) wl[k] = Wl[k * 256 + col];
#pragma unroll
    for (int k = 0; k < 64; k++) wr[k] = Wr[k * 256 + col];
    const float bbl = bl[col];
    const float bbr = br[col];

    __syncthreads();

#pragma unroll 2
    for (int r = 0; r < 32; r++) {
        const int row = base + r;
        float l0 = 0.f, l1 = 0.f, l2 = 0.f, l3 = 0.f;
        float r0 = 0.f, r1 = 0.f, r2 = 0.f, r3 = 0.f;
#pragma unroll
        for (int k4 = 0; k4 < 16; k4++) {
            const float4 xv = *(const float4*)&xs[r][k4 << 2];   // broadcast read
            l0 = fmaf(xv.x, wl[k4 * 4],     l0);
            l1 = fmaf(xv.y, wl[k4 * 4 + 1], l1);
            l2 = fmaf(xv.z, wl[k4 * 4 + 2], l2);
            l3 = fmaf(xv.w, wl[k4 * 4 + 3], l3);
            r0 = fmaf(xv.x, wr[k4 * 4],     r0);
            r1 = fmaf(xv.y, wr[k4 * 4 + 1], r1);
            r2 = fmaf(xv.z, wr[k4 * 4 + 2], r2);
            r3 = fmaf(xv.w, wr[k4 * 4 + 3], r3);
        }
        if (row < NN) {
            Yl[(long)row * 256 + col] = (l0 + l1) + (l2 + l3) + bbl;
            Yr[(long)row * 256 + col] = (r0 + r1) + (r2 + r3) + bbr;
        }
    }
}

// one edge's logit (pre-reduce): ez matvec + leaky + att dot
__device__ __forceinline__ float edge_part(const float ev[EDD], const float wreg[EDD][4],
                                           const float4 xlv, const float4 xrv,
                                           const float4 a4) {
    float e0 = 0.f, e1 = 0.f, e2 = 0.f, e3 = 0.f;
#pragma unroll
    for (int k = 0; k < EDD; k++) {
        e0 = fmaf(ev[k], wreg[k][0], e0);
        e1 = fmaf(ev[k], wreg[k][1], e1);
        e2 = fmaf(ev[k], wreg[k][2], e2);
        e3 = fmaf(ev[k], wreg[k][3], e3);
    }
    float s0 = xlv.x + xrv.x + e0;
    float s1 = xlv.y + xrv.y + e1;
    float s2 = xlv.z + xrv.z + e2;
    float s3 = xlv.w + xrv.w + e3;
    s0 = (s0 > 0.f) ? s0 : 0.2f * s0;
    s1 = (s1 > 0.f) ? s1 : 0.2f * s1;
    s2 = (s2 > 0.f) ? s2 : 0.2f * s2;
    s3 = (s3 > 0.f) ? s3 : 0.2f * s3;
    return fmaf(s0, a4.x, fmaf(s1, a4.y, fmaf(s2, a4.z, s3 * a4.w)));
}

// ---------- fused: edge logits + softmax (no-max) + aggregation + LN/GELU ----------
// x4 edge unroll with -inf masking (no tail code; srcs/ea_s padded so loads
// need no guards; exp(-inf)=0 makes masked edges contribute nothing).
// 16-lane reductions via DPP rotate (VALU-only) -> the edge loop has ZERO
// ds ops, so lgkmcnt tracks only the SMEM eav loads (one wait per 4 edges).
// Epilogue spread over all 64 lanes: 1 channel/lane -> 1 erf/lane (was 4).
__global__ __launch_bounds__(256, 4) void fused_edge_node_k(
    const int* __restrict__ wstart,
    const int* __restrict__ rowptr, const int* __restrict__ srcs,
    const float* __restrict__ ea_s,
    const float* __restrict__ We, const float* __restrict__ att,
    const float* __restrict__ xl, const float* __restrict__ xr,
    const float* __restrict__ bias, const float* __restrict__ lng,
    const float* __restrict__ lnb, const float* __restrict__ identity,
    float* __restrict__ x1out, float* __restrict__ outp, int mode)
{
    const int lane = threadIdx.x & 63;
    const int h    = lane >> 4;
    const int jj   = lane & 15;
    const int gc   = (h << 6) + (jj << 2);
    const int c    = (jj << 2) + h;          // this lane's epilogue channel

    // per-lane We columns (64 VGPRs), loaded once per wave
    float wreg[EDD][4];
#pragma unroll
    for (int k = 0; k < EDD; k++) {
        const float4 w4 = *(const float4*)(We + k * HC + gc);
        wreg[k][0] = w4.x; wreg[k][1] = w4.y; wreg[k][2] = w4.z; wreg[k][3] = w4.w;
    }
#pragma unroll
    for (int k = 0; k < EDD; k++)
#pragma unroll
        for (int j = 0; j < 4; j++) asm volatile("" : "+v"(wreg[k][j]));

    const float4 a4 = *(const float4*)(att + gc);
    // epilogue constants (per-lane channel c, node-independent)
    const float bb  = bias[c];
    const float gg  = lng[c];
    const float cc  = lnb[c];

    const int wid  = blockIdx.x * 4 + (threadIdx.x >> 6);
    const int nbeg = __builtin_amdgcn_readfirstlane(wstart[wid]);
    const int nend = __builtin_amdgcn_readfirstlane(wstart[wid + 1]);

    // scalar pipeline: rowptr one node ahead; first src-quad one node ahead
    int p0v = rowptr[nbeg];
    int p1v = rowptr[nbeg + 1];
    int q0 = srcs[p0v], q1 = srcs[p0v + 1], q2 = srcs[p0v + 2], q3 = srcs[p0v + 3];

    for (int n = nbeg; n < nend; n++) {
        const int p0 = __builtin_amdgcn_readfirstlane(p0v);
        const int p1 = __builtin_amdgcn_readfirstlane(p1v);
        p0v = p1;
        p1v = rowptr[(n + 2 <= NN) ? (n + 2) : NN];

        const float4 xrv = *(const float4*)(xr + (long)n * HC + gc);

        float dsum = 0.f;
        float ac0 = 0.f, ac1 = 0.f, ac2 = 0.f, ac3 = 0.f;

        for (int p = p0; p < p1; p += 4) {
            const int s0 = __builtin_amdgcn_readfirstlane(q0);
            const int s1 = __builtin_amdgcn_readfirstlane(q1);
            const int s2 = __builtin_amdgcn_readfirstlane(q2);
            const int s3 = __builtin_amdgcn_readfirstlane(q3);
            q0 = srcs[p + 4]; q1 = srcs[p + 5];    // prefetch next quad
            q2 = srcs[p + 6]; q3 = srcs[p + 7];

            const float4 x0 = *(const float4*)(xl + (long)s0 * HC + gc);
            const float4 x1 = *(const float4*)(xl + (long)s1 * HC + gc);
            const float4 x2 = *(const float4*)(xl + (long)s2 * HC + gc);
            const float4 x3 = *(const float4*)(xl + (long)s3 * HC + gc);

            const float4* __restrict__ e4 = (const float4*)(ea_s + (long)p * EDD);
            float ev0[EDD], ev1[EDD], ev2[EDD], ev3[EDD];
            *(float4*)&ev0[0] = e4[0];  *(float4*)&ev0[4] = e4[1];
            *(float4*)&ev0[8] = e4[2];  *(float4*)&ev0[12] = e4[3];
            *(float4*)&ev1[0] = e4[4];  *(float4*)&ev1[4] = e4[5];
            *(float4*)&ev1[8] = e4[6];  *(float4*)&ev1[12] = e4[7];
            *(float4*)&ev2[0] = e4[8];  *(float4*)&ev2[4] = e4[9];
            *(float4*)&ev2[8] = e4[10]; *(float4*)&ev2[12] = e4[11];
            *(float4*)&ev3[0] = e4[12]; *(float4*)&ev3[4] = e4[13];
            *(float4*)&ev3[8] = e4[14]; *(float4*)&ev3[12] = e4[15];

            float pt0 = edge_part(ev0, wreg, x0, xrv, a4);
            float pt1 = edge_part(ev1, wreg, x1, xrv, a4);
            float pt2 = edge_part(ev2, wreg, x2, xrv, a4);
            float pt3 = edge_part(ev3, wreg, x3, xrv, a4);

            // 16-lane sums, VALU-only (4 independent chains interleave)
            pt0 = row_sum16(pt0);
            pt1 = row_sum16(pt1);
            pt2 = row_sum16(pt2);
            pt3 = row_sum16(pt3);

            // mask tail edges: w = exp(-inf) = 0
            pt1 = (p + 1 < p1) ? pt1 : -INFINITY;
            pt2 = (p + 2 < p1) ? pt2 : -INFINITY;
            pt3 = (p + 3 < p1) ? pt3 : -INFINITY;

            const float w0 = fast_exp(pt0);
            const float w1 = fast_exp(pt1);
            const float w2 = fast_exp(pt2);
            const float w3 = fast_exp(pt3);
            dsum += (w0 + w1) + (w2 + w3);
            ac0 = fmaf(w0, x0.x, ac0); ac1 = fmaf(w0, x0.y, ac1);
            ac2 = fmaf(w0, x0.z, ac2); ac3 = fmaf(w0, x0.w, ac3);
            ac0 = fmaf(w1, x1.x, ac0); ac1 = fmaf(w1, x1.y, ac1);
            ac2 = fmaf(w1, x1.z, ac2); ac3 = fmaf(w1, x1.w, ac3);
            ac0 = fmaf(w2, x2.x, ac0); ac1 = fmaf(w2, x2.y, ac1);
            ac2 = fmaf(w2, x2.z, ac2); ac3 = fmaf(w2, x2.w, ac3);
            ac0 = fmaf(w3, x3.x, ac0); ac1 = fmaf(w3, x3.y, ac1);
            ac2 = fmaf(w3, x3.z, ac2); ac3 = fmaf(w3, x3.w, ac3);
        }

        // reload first quad for the NEXT node (covered by epilogue latency)
        q0 = srcs[p1];     q1 = srcs[p1 + 1];
        q2 = srcs[p1 + 2]; q3 = srcs[p1 + 3];

        const float inv = 1.0f / (dsum + 1e-16f);
        float v0 = ac0 * inv, v1 = ac1 * inv, v2 = ac2 * inv, v3 = ac3 * inv;

        // head mean across the 4 groups (every lane ends with the sums)
        v0 += __shfl_xor(v0, 16, 64); v0 += __shfl_xor(v0, 32, 64);
        v1 += __shfl_xor(v1, 16, 64); v1 += __shfl_xor(v1, 32, 64);
        v2 += __shfl_xor(v2, 16, 64); v2 += __shfl_xor(v2, 32, 64);
        v3 += __shfl_xor(v3, 16, 64); v3 += __shfl_xor(v3, 32, 64);

        // lane keeps channel c = 4*jj + h; LN over all 64 channels
        float vv = (h == 0) ? v0 : (h == 1) ? v1 : (h == 2) ? v2 : v3;
        vv = vv * 0.25f + bb;

        float s = row_sum16(vv);
        s += __shfl_xor(s, 16, 64); s += __shfl_xor(s, 32, 64);
        const float mu = s * (1.0f / 64.0f);
        const float d  = vv - mu;
        float qv = row_sum16(d * d);
        qv += __shfl_xor(qv, 16, 64); qv += __shfl_xor(qv, 32, 64);
        const float rs = rsqrtf(qv * (1.0f / 64.0f) + 1e-5f);

        const float y = d * rs * gg + cc;
        if (mode == 0) {
            x1out[(long)n * DD + c] = gelu_exact(y);
        } else {
            const float id = identity[(long)n * DD + c];
            outp[(long)n * DD + c] = gelu_exact(y + id);
        }
    }
}

// ---------- launch ----------
extern "C" void kernel_launch(void* const* d_in, const int* in_sizes, int n_in,
                              void* d_out, int out_size, void* d_ws, size_t ws_size,
                              hipStream_t stream) {
    (void)in_sizes; (void)n_in; (void)out_size; (void)ws_size;

    const float* h     = (const float*)d_in[0];
    const int*   ei    = (const int*)d_in[1];
    const float* ea    = (const float*)d_in[2];
    const float* g1Wl  = (const float*)d_in[3];
    const float* g1bl  = (const float*)d_in[4];
    const float* g1Wr  = (const float*)d_in[5];
    const float* g1br  = (const float*)d_in[6];
    const float* g1We  = (const float*)d_in[7];
    const float* g1att = (const float*)d_in[8];
    const float* g1bias= (const float*)d_in[9];
    const float* ln1g  = (const float*)d_in[10];
    const float* ln1b  = (const float*)d_in[11];
    const float* g2Wl  = (const float*)d_in[12];
    const float* g2bl  = (const float*)d_in[13];
    const float* g2Wr  = (const float*)d_in[14];
    const float* g2br  = (const float*)d_in[15];
    const float* g2We  = (const float*)d_in[16];
    const float* g2att = (const float*)d_in[17];
    const float* g2bias= (const float*)d_in[18];
    const float* ln2g  = (const float*)d_in[19];
    const float* ln2b  = (const float*)d_in[20];

    float* out = (float*)d_out;

    const int FUSED_BLOCKS = 4096;              // 16384 waves, ~25 edges each
    const int NW  = FUSED_BLOCKS * 4;
    const int CPE = (EE + NW - 1) / NW;

    // workspace layout (4-byte units)
    float* ws = (float*)d_ws;
    size_t o = 0;
    float* xl     = ws + o;         o += 12800000;   // N*256
    float* xr     = ws + o;         o += 12800000;   // N*256
    float* x1     = ws + o;         o += 3200000;    // N*64
    int*   rowptr = (int*)(ws + o); o += 50004;      // N+1 (+3 pad)
    int*   deg    = (int*)(ws + o); o += 50000;
    int*   cursor = (int*)(ws + o); o += 50000;
    int*   bsum   = (int*)(ws + o); o += 256;
    int*   srcs   = (int*)(ws + o); o += 400016;     // E + 16 pad (zeroed)
    int*   wstart = (int*)(ws + o); o += NW + 8;     // wave node ranges
    float* ea_s   = ws + o;         o += 6400064;    // E*16 + 4 pad rows

    const int GEMM_BLOCKS  = (NN + 31) / 32;    // 1563
    const int SCAN_BLOCKS  = (NN + 255) / 256;  // 196
    const int EDGE_BLOCKS  = (EE + 255) / 256;  // 1563
    const int WR_BLOCKS    = (NW + 1 + 255) / 256;

    // ----- CSR build (once; graph identical for both layers) -----
    fill_u32<<<256, 256, 0, stream>>>((unsigned*)deg, 0u, NN);
    hist_k<<<EDGE_BLOCKS, 256, 0, stream>>>(ei, deg);
    scan1_k<<<SCAN_BLOCKS, 256, 0, stream>>>(deg, rowptr, bsum);
    scan2_k<<<1, 256, 0, stream>>>(bsum, SCAN_BLOCKS);
    scan3_k<<<SCAN_BLOCKS, 256, 0, stream>>>(rowptr, bsum, cursor);
    wrange_k<<<WR_BLOCKS, 256, 0, stream>>>(rowptr, wstart, srcs, NW, CPE);
    scatter_k<<<EDGE_BLOCKS, 256, 0, stream>>>(ei, cursor, ea, srcs, ea_s);

    // ----- layer 1 -----
    gemm_node_lr<<<GEMM_BLOCKS, 256, 0, stream>>>(h, g1Wl, g1bl, g1Wr, g1br, xl, xr);
    fused_edge_node_k<<<FUSED_BLOCKS, 256, 0, stream>>>(wstart, rowptr, srcs, ea_s,
                                                        g1We, g1att, xl, xr,
                                                        g1bias, ln1g, ln1b,
                                                        h, x1, out, 0);

    // ----- layer 2 -----
    gemm_node_lr<<<GEMM_BLOCKS, 256, 0, stream>>>(x1, g2Wl, g2bl, g2Wr, g2br, xl, xr);
    fused_edge_node_k<<<FUSED_BLOCKS, 256, 0, stream>>>(wstart, rowptr, srcs, ea_s,
                                                        g2We, g2att, xl, xr,
                                                        g2bias, ln2g, ln2b,
                                                        h, x1, out, 1);
}

// Round 6
// 509.562 us; speedup vs baseline: 1.0250x; 1.0250x over previous
//
#include <hip/hip_runtime.h>
#include <math.h>

// Problem constants (fixed by reference setup_inputs)
#define NN  50000
#define EE  400000
#define DD  64
#define HH  4
#define HC  256      // H * C
#define EDD 16
#define CAPE 96      // staged edges per wave (cpe ~25 + max degree ~30 << 96)

__device__ __forceinline__ float gelu_exact(float x) {
    return 0.5f * x * (1.0f + erff(x * 0.70710678118654752440f));
}
// fast exp via v_exp_f32: exp(x)=2^(x*log2e). exp2(-inf)=0 preserved.
__device__ __forceinline__ float fast_exp(float x) {
    return __builtin_amdgcn_exp2f(x * 1.44269504088896340736f);
}

// DPP rotate-reduce within each 16-lane row: VALU-only (no ds_swizzle, no
// lgkmcnt). Sum of all 16 lanes of the row ends up in every lane.
template <int CTRL>
__device__ __forceinline__ float dpp_add(float x) {
    const int t = __builtin_amdgcn_update_dpp(0, __float_as_int(x), CTRL, 0xF, 0xF, true);
    return x + __int_as_float(t);
}
__device__ __forceinline__ float row_sum16(float x) {
    x = dpp_add<0x128>(x);   // row_ror:8
    x = dpp_add<0x124>(x);   // row_ror:4
    x = dpp_add<0x122>(x);   // row_ror:2
    x = dpp_add<0x121>(x);   // row_ror:1
    return x;
}

// ---------- fills ----------
__global__ void fill_u32(unsigned* __restrict__ p, unsigned v, int n) {
    int i = blockIdx.x * blockDim.x + threadIdx.x;
    int s = gridDim.x * blockDim.x;
    for (; i < n; i += s) p[i] = v;
}

// ---------- CSR build ----------
__global__ void hist_k(const int* __restrict__ ei, int* __restrict__ deg) {
    int e = blockIdx.x * 256 + threadIdx.x;
    if (e < EE) atomicAdd(&deg[ei[EE + e]], 1);
}
__global__ void scan1_k(const int* __restrict__ deg, int* __restrict__ rowptr,
                        int* __restrict__ bsum) {
    __shared__ int s[256];
    int t = threadIdx.x, i = blockIdx.x * 256 + t;
    int v = (i < NN) ? deg[i] : 0;
    s[t] = v; __syncthreads();
    for (int o = 1; o < 256; o <<= 1) {
        int u = (t >= o) ? s[t - o] : 0;
        __syncthreads();
        s[t] += u;
        __syncthreads();
    }
    if (i < NN) rowptr[i] = s[t] - v;
    if (t == 255) bsum[blockIdx.x] = s[255];
}
__global__ void scan2_k(int* __restrict__ bsum, int nb) {
    __shared__ int s[256];
    int t = threadIdx.x;
    int v = (t < nb) ? bsum[t] : 0;
    s[t] = v; __syncthreads();
    for (int o = 1; o < 256; o <<= 1) {
        int u = (t >= o) ? s[t - o] : 0;
        __syncthreads();
        s[t] += u;
        __syncthreads();
    }
    if (t < nb) bsum[t] = s[t] - v;
}
__global__ void scan3_k(int* __restrict__ rowptr, const int* __restrict__ bsum,
                        int* __restrict__ cursor) {
    int i = blockIdx.x * 256 + threadIdx.x;
    if (i < NN) {
        int r = rowptr[i] + bsum[blockIdx.x];
        rowptr[i] = r;
        cursor[i] = r;
    }
    if (i == 0) rowptr[NN] = EE;
}
// scatter srcs AND edge_attr into CSR order
__global__ void scatter_k(const int* __restrict__ ei, int* __restrict__ cursor,
                          const float* __restrict__ ea,
                          int* __restrict__ srcs, float* __restrict__ ea_s) {
    int e = blockIdx.x * 256 + threadIdx.x;
    if (e >= EE) return;
    int dst = ei[EE + e];
    int pos = atomicAdd(&cursor[dst], 1);
    srcs[pos] = ei[e];
    const float4* s4 = (const float4*)(ea + (long)e * EDD);
    float4* d4 = (float4*)(ea_s + (long)pos * EDD);
    d4[0] = s4[0]; d4[1] = s4[1]; d4[2] = s4[2]; d4[3] = s4[3];
}

// wave -> node-range precompute; also zeroes the srcs pad (valid node 0) so
// scalar prefetches past EE need no guards.
__global__ void wrange_k(const int* __restrict__ rowptr, int* __restrict__ wstart,
                         int* __restrict__ srcs, int nw, int cpe) {
    int w = blockIdx.x * 256 + threadIdx.x;
    if (blockIdx.x == 0 && threadIdx.x < 16) srcs[EE + threadIdx.x] = 0;
    if (w > nw) return;
    if (w == nw) { wstart[nw] = NN; return; }
    const int lo = w * cpe;
    int l = 0, r = NN;
    while (l < r) { int m = (l + r) >> 1; if (rowptr[m] >= lo) r = m; else l = m + 1; }
    wstart[w] = l;
}

// ---------- node GEMM (merged l+r): Y{l,r}[N,256] = X[N,64] @ W{l,r} + b{l,r} ----------
// X tile staged in LDS via per-lane coalesced loads (vmcnt path, not SMEM);
// ds_read broadcasts get fine-grained lgkmcnt waits. Both W sets in regs.
__global__ __launch_bounds__(256) void gemm_node_lr(
    const float* __restrict__ X,
    const float* __restrict__ Wl, const float* __restrict__ bl,
    const float* __restrict__ Wr, const float* __restrict__ br,
    float* __restrict__ Yl, float* __restrict__ Yr)
{
    __shared__ float xs[32][64];      // 8 KB tile
    const int tid  = threadIdx.x;
    const int col  = tid;
    const int base = blockIdx.x * 32;

    // stage X tile: 512 float4, 256 threads -> 2 each (coalesced, per-lane)
#pragma unroll
    for (int i = 0; i < 2; i++) {
        const int f   = tid + i * 256;         // float4 index 0..511
        const int r   = f >> 4;
        const int row = base + r;
        const int rr  = (row < NN) ? row : (NN - 1);
        const float4 v = *(const float4*)(X + (long)rr * 64 + ((f & 15) << 2));
        *(float4*)&xs[r][(f & 15) << 2] = v;
    }

    // both W columns into registers (128 VGPRs)
    float wl[64], wr[64];
#pragma unroll
    for (int k = 0; k < 64; k++) wl[k] = Wl[k * 256 + col];
#pragma unroll
    for (int k = 0; k < 64; k++) wr[k] = Wr[k * 256 + col];
    const float bbl = bl[col];
    const float bbr = br[col];

    __syncthreads();

#pragma unroll 2
    for (int r = 0; r < 32; r++) {
        const int row = base + r;
        float l0 = 0.f, l1 = 0.f, l2 = 0.f, l3 = 0.f;
        float r0 = 0.f, r1 = 0.f, r2 = 0.f, r3 = 0.f;
#pragma unroll
        for (int k4 = 0; k4 < 16; k4++) {
            const float4 xv = *(const float4*)&xs[r][k4 << 2];   // broadcast read
            l0 = fmaf(xv.x, wl[k4 * 4],     l0);
            l1 = fmaf(xv.y, wl[k4 * 4 + 1], l1);
            l2 = fmaf(xv.z, wl[k4 * 4 + 2], l2);
            l3 = fmaf(xv.w, wl[k4 * 4 + 3], l3);
            r0 = fmaf(xv.x, wr[k4 * 4],     r0);
            r1 = fmaf(xv.y, wr[k4 * 4 + 1], r1);
            r2 = fmaf(xv.z, wr[k4 * 4 + 2], r2);
            r3 = fmaf(xv.w, wr[k4 * 4 + 3], r3);
        }
        if (row < NN) {
            Yl[(long)row * 256 + col] = (l0 + l1) + (l2 + l3) + bbl;
            Yr[(long)row * 256 + col] = (r0 + r1) + (r2 + r3) + bbr;
        }
    }
}

// one edge's logit (pre-reduce): ez matvec + leaky + att dot
__device__ __forceinline__ float edge_part(const float ev[EDD], const float wreg[EDD][4],
                                           const float4 xlv, const float4 xrv,
                                           const float4 a4) {
    float e0 = 0.f, e1 = 0.f, e2 = 0.f, e3 = 0.f;
#pragma unroll
    for (int k = 0; k < EDD; k++) {
        e0 = fmaf(ev[k], wreg[k][0], e0);
        e1 = fmaf(ev[k], wreg[k][1], e1);
        e2 = fmaf(ev[k], wreg[k][2], e2);
        e3 = fmaf(ev[k], wreg[k][3], e3);
    }
    float s0 = xlv.x + xrv.x + e0;
    float s1 = xlv.y + xrv.y + e1;
    float s2 = xlv.z + xrv.z + e2;
    float s3 = xlv.w + xrv.w + e3;
    s0 = (s0 > 0.f) ? s0 : 0.2f * s0;
    s1 = (s1 > 0.f) ? s1 : 0.2f * s1;
    s2 = (s2 > 0.f) ? s2 : 0.2f * s2;
    s3 = (s3 > 0.f) ? s3 : 0.2f * s3;
    return fmaf(s0, a4.x, fmaf(s1, a4.y, fmaf(s2, a4.z, s3 * a4.w)));
}

// ---------- fused: edge logits + softmax (no-max) + aggregation + LN/GELU ----------
// R5 post-mortem: wave-uniform ea loads compile to s_load (SMEM); SMEM
// returns out-of-order so the only wait is lgkmcnt(0), issued and consumed
// in the SAME iteration -> ~250 cy exposed stall per pair. Fix: stage the
// wave's contiguous edge slice of ea_s into LDS ONCE (per-lane coalesced
// float4 loads, one vmcnt wait), read in-loop via uniform-address
// ds_read_b128 (broadcast, partial lgkmcnt waits, prefetchable).
// x2 pair loop with guarded tail (the x4 masked unroll of R5 added ~19%
// edge overwork on Poisson(8) degrees - reverted). DPP row reduce and
// 64-lane epilogue kept from R5.
__global__ __launch_bounds__(256, 4) void fused_edge_node_k(
    const int* __restrict__ wstart,
    const int* __restrict__ rowptr, const int* __restrict__ srcs,
    const float* __restrict__ ea_s,
    const float* __restrict__ We, const float* __restrict__ att,
    const float* __restrict__ xl, const float* __restrict__ xr,
    const float* __restrict__ bias, const float* __restrict__ lng,
    const float* __restrict__ lnb, const float* __restrict__ identity,
    float* __restrict__ x1out, float* __restrict__ outp, int mode)
{
    __shared__ float eabuf[4][CAPE * EDD];    // 24 KB: per-wave ea slice
    const int lane  = threadIdx.x & 63;
    const int wslot = threadIdx.x >> 6;
    const int h     = lane >> 4;
    const int jj    = lane & 15;
    const int gc    = (h << 6) + (jj << 2);
    const int c     = (jj << 2) + h;          // this lane's epilogue channel

    // per-lane We columns (64 VGPRs), loaded once per wave
    float wreg[EDD][4];
#pragma unroll
    for (int k = 0; k < EDD; k++) {
        const float4 w4 = *(const float4*)(We + k * HC + gc);
        wreg[k][0] = w4.x; wreg[k][1] = w4.y; wreg[k][2] = w4.z; wreg[k][3] = w4.w;
    }
#pragma unroll
    for (int k = 0; k < EDD; k++)
#pragma unroll
        for (int j = 0; j < 4; j++) asm volatile("" : "+v"(wreg[k][j]));

    const float4 a4 = *(const float4*)(att + gc);
    const float bb  = bias[c];
    const float gg  = lng[c];
    const float cc  = lnb[c];

    const int wid  = blockIdx.x * 4 + wslot;
    const int nbeg = __builtin_amdgcn_readfirstlane(wstart[wid]);
    const int nend = __builtin_amdgcn_readfirstlane(wstart[wid + 1]);

    // ---- stage this wave's edge slice of ea_s into LDS (wave-private) ----
    const int estart = __builtin_amdgcn_readfirstlane(rowptr[nbeg]);
    const int eend   = __builtin_amdgcn_readfirstlane(rowptr[nend]);
    int nstage = eend - estart;
    if (nstage > CAPE) nstage = CAPE;         // overflow edges fall back to global
    {
        const float4* __restrict__ gsrc = (const float4*)(ea_s + (long)estart * EDD);
        float4* l4 = (float4*)&eabuf[wslot][0];
        for (int i = lane; i < nstage * 4; i += 64) l4[i] = gsrc[i];
    }
    const int cap_end = estart + CAPE;
    const float* lbase = &eabuf[wslot][0];
    // no barrier: buffer is wave-private; DS ops are in-order per wave

    // scalar pipeline: rowptr one node ahead; first src-pair one node ahead
    int p0v = rowptr[nbeg];
    int p1v = rowptr[nbeg + 1];
    int sAn = srcs[p0v];
    int sBn = srcs[p0v + 1];

    for (int n = nbeg; n < nend; n++) {
        const int p0 = __builtin_amdgcn_readfirstlane(p0v);
        const int p1 = __builtin_amdgcn_readfirstlane(p1v);
        p0v = p1;
        p1v = rowptr[(n + 2 <= NN) ? (n + 2) : NN];
        int sA = sAn, sB = sBn;
        sAn = srcs[p1];
        sBn = srcs[p1 + 1];

        const float4 xrv = *(const float4*)(xr + (long)n * HC + gc);

        float dsum = 0.f;
        float ac0 = 0.f, ac1 = 0.f, ac2 = 0.f, ac3 = 0.f;

        int p = p0;
        for (; p + 1 < p1; p += 2) {
            const int srcA = __builtin_amdgcn_readfirstlane(sA);
            const int srcB = __builtin_amdgcn_readfirstlane(sB);
            sA = srcs[p + 2];                       // prefetch next pair
            sB = srcs[p + 3];

            const float4 xA = *(const float4*)(xl + (long)srcA * HC + gc);
            const float4 xB = *(const float4*)(xl + (long)srcB * HC + gc);

            float evA[EDD], evB[EDD];
            if (p + 1 < cap_end) {                  // LDS fast path (uniform branch)
                const float4* __restrict__ e4 = (const float4*)(lbase + (p - estart) * EDD);
                *(float4*)&evA[0]  = e4[0];  *(float4*)&evA[4]  = e4[1];
                *(float4*)&evA[8]  = e4[2];  *(float4*)&evA[12] = e4[3];
                *(float4*)&evB[0]  = e4[4];  *(float4*)&evB[4]  = e4[5];
                *(float4*)&evB[8]  = e4[6];  *(float4*)&evB[12] = e4[7];
            } else {                                // overflow (rare)
                const float4* __restrict__ e4 = (const float4*)(ea_s + (long)p * EDD);
                *(float4*)&evA[0]  = e4[0];  *(float4*)&evA[4]  = e4[1];
                *(float4*)&evA[8]  = e4[2];  *(float4*)&evA[12] = e4[3];
                *(float4*)&evB[0]  = e4[4];  *(float4*)&evB[4]  = e4[5];
                *(float4*)&evB[8]  = e4[6];  *(float4*)&evB[12] = e4[7];
            }

            float ptA = edge_part(evA, wreg, xA, xrv, a4);
            float ptB = edge_part(evB, wreg, xB, xrv, a4);

            ptA = row_sum16(ptA);                   // VALU-only reduce
            ptB = row_sum16(ptB);

            const float wA = fast_exp(ptA);
            const float wB = fast_exp(ptB);
            dsum += (wA + wB);
            ac0 = fmaf(wA, xA.x, ac0); ac1 = fmaf(wA, xA.y, ac1);
            ac2 = fmaf(wA, xA.z, ac2); ac3 = fmaf(wA, xA.w, ac3);
            ac0 = fmaf(wB, xB.x, ac0); ac1 = fmaf(wB, xB.y, ac1);
            ac2 = fmaf(wB, xB.z, ac2); ac3 = fmaf(wB, xB.w, ac3);
        }

        if (p < p1) {   // odd tail
            const int src = __builtin_amdgcn_readfirstlane(sA);
            const float4 xv = *(const float4*)(xl + (long)src * HC + gc);
            float ev[EDD];
            if (p < cap_end) {
                const float4* __restrict__ e4 = (const float4*)(lbase + (p - estart) * EDD);
                *(float4*)&ev[0]  = e4[0];  *(float4*)&ev[4]  = e4[1];
                *(float4*)&ev[8]  = e4[2];  *(float4*)&ev[12] = e4[3];
            } else {
                const float4* __restrict__ e4 = (const float4*)(ea_s + (long)p * EDD);
                *(float4*)&ev[0]  = e4[0];  *(float4*)&ev[4]  = e4[1];
                *(float4*)&ev[8]  = e4[2];  *(float4*)&ev[12] = e4[3];
            }
            float pt = edge_part(ev, wreg, xv, xrv, a4);
            pt = row_sum16(pt);
            const float w = fast_exp(pt);
            dsum += w;
            ac0 = fmaf(w, xv.x, ac0); ac1 = fmaf(w, xv.y, ac1);
            ac2 = fmaf(w, xv.z, ac2); ac3 = fmaf(w, xv.w, ac3);
        }

        const float inv = 1.0f / (dsum + 1e-16f);
        float v0 = ac0 * inv, v1 = ac1 * inv, v2 = ac2 * inv, v3 = ac3 * inv;

        // head mean across the 4 groups (every lane ends with the sums)
        v0 += __shfl_xor(v0, 16, 64); v0 += __shfl_xor(v0, 32, 64);
        v1 += __shfl_xor(v1, 16, 64); v1 += __shfl_xor(v1, 32, 64);
        v2 += __shfl_xor(v2, 16, 64); v2 += __shfl_xor(v2, 32, 64);
        v3 += __shfl_xor(v3, 16, 64); v3 += __shfl_xor(v3, 32, 64);

        // lane keeps channel c = 4*jj + h; LN over all 64 channels
        float vv = (h == 0) ? v0 : (h == 1) ? v1 : (h == 2) ? v2 : v3;
        vv = vv * 0.25f + bb;

        float s = row_sum16(vv);
        s += __shfl_xor(s, 16, 64); s += __shfl_xor(s, 32, 64);
        const float mu = s * (1.0f / 64.0f);
        const float d  = vv - mu;
        float qv = row_sum16(d * d);
        qv += __shfl_xor(qv, 16, 64); qv += __shfl_xor(qv, 32, 64);
        const float rs = rsqrtf(qv * (1.0f / 64.0f) + 1e-5f);

        const float y = d * rs * gg + cc;
        if (mode == 0) {
            x1out[(long)n * DD + c] = gelu_exact(y);
        } else {
            const float id = identity[(long)n * DD + c];
            outp[(long)n * DD + c] = gelu_exact(y + id);
        }
    }
}

// ---------- launch ----------
extern "C" void kernel_launch(void* const* d_in, const int* in_sizes, int n_in,
                              void* d_out, int out_size, void* d_ws, size_t ws_size,
                              hipStream_t stream) {
    (void)in_sizes; (void)n_in; (void)out_size; (void)ws_size;

    const float* h     = (const float*)d_in[0];
    const int*   ei    = (const int*)d_in[1];
    const float* ea    = (const float*)d_in[2];
    const float* g1Wl  = (const float*)d_in[3];
    const float* g1bl  = (const float*)d_in[4];
    const float* g1Wr  = (const float*)d_in[5];
    const float* g1br  = (const float*)d_in[6];
    const float* g1We  = (const float*)d_in[7];
    const float* g1att = (const float*)d_in[8];
    const float* g1bias= (const float*)d_in[9];
    const float* ln1g  = (const float*)d_in[10];
    const float* ln1b  = (const float*)d_in[11];
    const float* g2Wl  = (const float*)d_in[12];
    const float* g2bl  = (const float*)d_in[13];
    const float* g2Wr  = (const float*)d_in[14];
    const float* g2br  = (const float*)d_in[15];
    const float* g2We  = (const float*)d_in[16];
    const float* g2att = (const float*)d_in[17];
    const float* g2bias= (const float*)d_in[18];
    const float* ln2g  = (const float*)d_in[19];
    const float* ln2b  = (const float*)d_in[20];

    float* out = (float*)d_out;

    const int FUSED_BLOCKS = 4096;              // 16384 waves, ~25 edges each
    const int NW  = FUSED_BLOCKS * 4;
    const int CPE = (EE + NW - 1) / NW;

    // workspace layout (4-byte units)
    float* ws = (float*)d_ws;
    size_t o = 0;
    float* xl     = ws + o;         o += 12800000;   // N*256
    float* xr     = ws + o;         o += 12800000;   // N*256
    float* x1     = ws + o;         o += 3200000;    // N*64
    int*   rowptr = (int*)(ws + o); o += 50004;      // N+1 (+3 pad)
    int*   deg    = (int*)(ws + o); o += 50000;
    int*   cursor = (int*)(ws + o); o += 50000;
    int*   bsum   = (int*)(ws + o); o += 256;
    int*   srcs   = (int*)(ws + o); o += 400016;     // E + 16 pad (zeroed)
    int*   wstart = (int*)(ws + o); o += NW + 8;     // wave node ranges
    float* ea_s   = ws + o;         o += 6400064;    // E*16 + pad

    const int GEMM_BLOCKS  = (NN + 31) / 32;    // 1563
    const int SCAN_BLOCKS  = (NN + 255) / 256;  // 196
    const int EDGE_BLOCKS  = (EE + 255) / 256;  // 1563
    const int WR_BLOCKS    = (NW + 1 + 255) / 256;

    // ----- CSR build (once; graph identical for both layers) -----
    fill_u32<<<256, 256, 0, stream>>>((unsigned*)deg, 0u, NN);
    hist_k<<<EDGE_BLOCKS, 256, 0, stream>>>(ei, deg);
    scan1_k<<<SCAN_BLOCKS, 256, 0, stream>>>(deg, rowptr, bsum);
    scan2_k<<<1, 256, 0, stream>>>(bsum, SCAN_BLOCKS);
    scan3_k<<<SCAN_BLOCKS, 256, 0, stream>>>(rowptr, bsum, cursor);
    wrange_k<<<WR_BLOCKS, 256, 0, stream>>>(rowptr, wstart, srcs, NW, CPE);
    scatter_k<<<EDGE_BLOCKS, 256, 0, stream>>>(ei, cursor, ea, srcs, ea_s);

    // ----- layer 1 -----
    gemm_node_lr<<<GEMM_BLOCKS, 256, 0, stream>>>(h, g1Wl, g1bl, g1Wr, g1br, xl, xr);
    fused_edge_node_k<<<FUSED_BLOCKS, 256, 0, stream>>>(wstart, rowptr, srcs, ea_s,
                                                        g1We, g1att, xl, xr,
                                                        g1bias, ln1g, ln1b,
                                                        h, x1, out, 0);

    // ----- layer 2 -----
    gemm_node_lr<<<GEMM_BLOCKS, 256, 0, stream>>>(x1, g2Wl, g2bl, g2Wr, g2br, xl, xr);
    fused_edge_node_k<<<FUSED_BLOCKS, 256, 0, stream>>>(wstart, rowptr, srcs, ea_s,
                                                        g2We, g2att, xl, xr,
                                                        g2bias, ln2g, ln2b,
                                                        h, x1, out, 1);
}